// Round 12
// baseline (1442.106 us; speedup 1.0000x reference)
//
#include <hip/hip_runtime.h>
#include <math.h>

// Problem constants
#define TT 256      // sequence length
#define BB 64       // batch
#define DD 300      // embedding dim
#define KP0 320     // layer-0 K padded to multiple of 32
#define HH 256      // hidden
#define KK 37       // CRF states
#define FH 1024     // 4*H
#define MTOT (TT*BB) // 16384 rows, time-major r = t*64 + b

typedef __attribute__((ext_vector_type(8))) short short8;  // 8 bf16 (4 VGPR) MFMA A/B frag
typedef __attribute__((ext_vector_type(4))) float f32x4;   // MFMA C/D frag

// ---------- bf16 helpers ----------
__device__ __forceinline__ float bf2f(unsigned short u) {
    union { float f; unsigned int i; } v; v.i = ((unsigned int)u) << 16; return v.f;
}
__device__ __forceinline__ unsigned short f2bf(float f) {
    union { float f; unsigned int i; } v; v.f = f;
    unsigned int i = v.i;
    unsigned int r = (i + 0x7FFFu + ((i >> 16) & 1u)) >> 16; // RNE
    return (unsigned short)r;
}
__device__ __forceinline__ float sigm(float x)   { return 1.0f / (1.0f + __expf(-x)); }
__device__ __forceinline__ float tanh_f(float x) { return 2.0f / (1.0f + __expf(-2.0f * x)) - 1.0f; }

// signed byte extract (compiler -> v_bfe_i32)
__device__ __forceinline__ int sb0(int w) { return (w << 24) >> 24; }
__device__ __forceinline__ int sb1(int w) { return (w << 16) >> 24; }
__device__ __forceinline__ int sb2(int w) { return (w <<  8) >> 24; }
__device__ __forceinline__ int sb3(int w) { return  w        >> 24; }

#if defined(__has_builtin)
#if __has_builtin(__builtin_amdgcn_sdot4)
#define HAVE_SDOT4 1
#endif
#endif

// 4x int8 dot product: c += dot(a.bytes, b.bytes)
__device__ __forceinline__ int dot4i8(int a, int b, int c) {
#ifdef HAVE_SDOT4
    return __builtin_amdgcn_sdot4(a, b, c, false);
#else
    return c + sb0(a) * sb0(b) + sb1(a) * sb1(b) + sb2(a) * sb2(b) + sb3(a) * sb3(b);
#endif
}

// accumulate 4 gates for one h-dword against one weight int4
__device__ __forceinline__ void lstm_dot(int hw, int4 wv, int& a0, int& a1, int& a2, int& a3) {
    a0 = dot4i8(hw, wv.x, a0);
    a1 = dot4i8(hw, wv.y, a1);
    a2 = dot4i8(hw, wv.z, a2);
    a3 = dot4i8(hw, wv.w, a3);
}

// barrier that waits only on LDS ops (lgkmcnt), NOT on global loads/stores.
__device__ __forceinline__ void barrier_lgkm() {
    asm volatile("s_waitcnt lgkmcnt(0)\n\ts_barrier" ::: "memory");
}

// permute gate-major col (g*256+unit) -> interleaved (unit*4+g)
__device__ __forceinline__ int perm_col(int nn) { return ((nn & 255) << 2) | (nn >> 8); }

// ---------- prep: FUSED per-row scale + int8 quantize of Whh ----------
__global__ __launch_bounds__(64) void conv_quant(
    const float* __restrict__ w0f, const float* __restrict__ w0b,
    const float* __restrict__ w1f, const float* __restrict__ w1b,
    float* __restrict__ S, unsigned int* __restrict__ WQ)
{
    const int m = blockIdx.x >> 10;
    const int r = blockIdx.x & 1023;          // r = g*256 + u
    const float* W = m == 0 ? w0f : m == 1 ? w0b : m == 2 ? w1f : w1b;
    const int t = threadIdx.x;
    const float4 wv = *(const float4*)(W + r * HH + t * 4);  // this thread's 4 k's
    float mx = fmaxf(fmaxf(fabsf(wv.x), fabsf(wv.y)), fmaxf(fabsf(wv.z), fabsf(wv.w)));
    #pragma unroll
    for (int s = 32; s > 0; s >>= 1) mx = fmaxf(mx, __shfl_down(mx, s, 64));
    const float mxall = __shfl(mx, 0, 64);
    const float s = fmaxf(mxall, 1e-20f) / 127.0f;
    const int g = r >> 8, u = r & 255;
    if (t == 0) S[m * 1024 + u * 4 + g] = s;
    int q0 = (int)rintf(wv.x / s), q1 = (int)rintf(wv.y / s);
    int q2 = (int)rintf(wv.z / s), q3 = (int)rintf(wv.w / s);
    q0 = max(-127, min(127, q0)); q1 = max(-127, min(127, q1));
    q2 = max(-127, min(127, q2)); q3 = max(-127, min(127, q3));
    WQ[m * 65536 + (t * 256 + u) * 4 + g] =
        (unsigned int)(q0 & 0xff) | ((unsigned int)(q1 & 0xff) << 8) |
        ((unsigned int)(q2 & 0xff) << 16) | ((unsigned int)(q3 & 0xff) << 24);
}

// ---------- prep: Wsbj f32 (37x512) -> bf16 padded (64x512), rows>=37 zero ----------
__global__ __launch_bounds__(256) void conv_wsbj_bf(
    const float* __restrict__ Wsbj, unsigned short* __restrict__ WB)
{
    const int idx = blockIdx.x * 256 + threadIdx.x;   // 0 .. 64*512-1
    if (idx >= 64 * 512) return;
    const int r = idx >> 9, cidx = idx & 511;
    WB[idx] = (r < KK) ? f2bf(Wsbj[r * 512 + cidx]) : (unsigned short)0;
}

// ---------- prep: gather embedding rows -> Abf bf16 [16384][320] (zero-pad k>=300) ----------
__global__ __launch_bounds__(320) void conv_gather(
    const int* __restrict__ text, const float* __restrict__ emb,
    unsigned short* __restrict__ Abf)
{
    const int r = blockIdx.x;
    const int k = threadIdx.x;
    const int t = r >> 6, b = r & 63;
    const int idx = text[b * TT + t];
    Abf[r * KP0 + k] = (k < DD) ? f2bf(emb[(size_t)idx * DD + k]) : (unsigned short)0;
}

// ---------- prep: 4x W f32 -> bf16 zero-padded, merged into one dispatch ----------
__global__ __launch_bounds__(256) void conv_w4(
    const float* __restrict__ s0, const float* __restrict__ s1,
    const float* __restrict__ s2, const float* __restrict__ s3,
    unsigned short* __restrict__ d0, unsigned short* __restrict__ d1,
    unsigned short* __restrict__ d2, unsigned short* __restrict__ d3)
{
    const int z = blockIdx.y;
    const float* src = z == 0 ? s0 : z == 1 ? s1 : z == 2 ? s2 : s3;
    unsigned short* dst = z == 0 ? d0 : z == 1 ? d1 : z == 2 ? d2 : d3;
    const int kin   = z < 2 ? DD  : 512;
    const int kout  = z < 2 ? KP0 : 512;
    const int total = 1024 * kout;
    const int idx = blockIdx.x * 256 + threadIdx.x;
    if (idx >= total) return;
    const int rr = idx / kout, k = idx - rr * kout;
    dst[idx] = (k < kin) ? f2bf(src[rr * kin + k]) : (unsigned short)0;
}

// ---------- MFMA GEMM (f+b merged on blockIdx.z): out_z = A @ W_z^T + bias_z ----------
__global__ __launch_bounds__(256) void gemm_mfma2(
    const unsigned short* __restrict__ A,
    const unsigned short* __restrict__ Wf,
    const unsigned short* __restrict__ Wb,
    const float* __restrict__ biasf,
    const float* __restrict__ biasb,
    unsigned short* __restrict__ outf,
    unsigned short* __restrict__ outb,
    int lda)
{
    const unsigned short* W = blockIdx.z ? Wb : Wf;
    const float* bias        = blockIdx.z ? biasb : biasf;
    unsigned short* out      = blockIdx.z ? outb : outf;

    const int bm = blockIdx.x * 128;
    const int bn = blockIdx.y * 128;
    const int tid = threadIdx.x;
    const int lane = tid & 63;
    const int wave = tid >> 6;
    const int wm = (wave & 1) * 64;
    const int wn = (wave >> 1) * 64;

    __shared__ __align__(16) unsigned short As[128 * 32];  // [row][k] 8 KB
    __shared__ __align__(16) unsigned short Bs[128 * 32];  // [wrow][k] 8 KB

    f32x4 acc[4][4] = {};

    const int srow = tid >> 2;          // 0..63
    const int sk = (tid & 3) * 8;       // k element offset (16 B granules)

    const unsigned short* ga0 = A + (size_t)(bm + srow) * lda + sk;
    const unsigned short* ga1 = A + (size_t)(bm + srow + 64) * lda + sk;
    const unsigned short* gb0 = W + (size_t)(bn + srow) * lda + sk;
    const unsigned short* gb1 = W + (size_t)(bn + srow + 64) * lda + sk;

    unsigned short* lA0 = As + wave * 512;
    unsigned short* lA1 = As + 2048 + wave * 512;
    unsigned short* lB0 = Bs + wave * 512;
    unsigned short* lB1 = Bs + 2048 + wave * 512;

    const int kiters = lda >> 5;
    for (int kb = 0; kb < kiters; kb++) {
        const int k0 = kb * 32;
        __builtin_amdgcn_global_load_lds(
            (const __attribute__((address_space(1))) unsigned int*)(ga0 + k0),
            (__attribute__((address_space(3))) unsigned int*)lA0, 16, 0, 0);
        __builtin_amdgcn_global_load_lds(
            (const __attribute__((address_space(1))) unsigned int*)(ga1 + k0),
            (__attribute__((address_space(3))) unsigned int*)lA1, 16, 0, 0);
        __builtin_amdgcn_global_load_lds(
            (const __attribute__((address_space(1))) unsigned int*)(gb0 + k0),
            (__attribute__((address_space(3))) unsigned int*)lB0, 16, 0, 0);
        __builtin_amdgcn_global_load_lds(
            (const __attribute__((address_space(1))) unsigned int*)(gb1 + k0),
            (__attribute__((address_space(3))) unsigned int*)lB1, 16, 0, 0);
        __syncthreads();

        short8 af[4], bfr[4];
        #pragma unroll
        for (int i = 0; i < 4; i++) {
            af[i]  = *(const short8*)&As[(wm + i * 16 + (lane & 15)) * 32 + (lane >> 4) * 8];
            bfr[i] = *(const short8*)&Bs[(wn + i * 16 + (lane & 15)) * 32 + (lane >> 4) * 8];
        }
        #pragma unroll
        for (int i = 0; i < 4; i++)
            #pragma unroll
            for (int j = 0; j < 4; j++)
                acc[i][j] = __builtin_amdgcn_mfma_f32_16x16x32_bf16(af[i], bfr[j], acc[i][j], 0, 0, 0);
        __syncthreads();
    }

    // C/D: col = lane&15, row = (lane>>4)*4 + reg  [measured m89/m91]
    const int cn = lane & 15;
    const int cr = (lane >> 4) * 4;
    #pragma unroll
    for (int j = 0; j < 4; j++) {
        const int n = bn + wn + j * 16 + cn;
        const float bv = bias[n];
        const int pc = perm_col(n);
        #pragma unroll
        for (int i = 0; i < 4; i++) {
            #pragma unroll
            for (int r = 0; r < 4; r++) {
                const int m = bm + wm + i * 16 + cr + r;
                out[(size_t)m * FH + pc] = f2bf(acc[i][j][r] + bv);
            }
        }
    }
}

// ---------- Emission GEMM: em = h1(16384x512 bf16) @ WsbjB(64x512 bf16)^T + bias, f32 out ----------
__global__ __launch_bounds__(256) void gemm_em(
    const unsigned short* __restrict__ A,
    const unsigned short* __restrict__ W,
    const float* __restrict__ bias,
    float* __restrict__ em)
{
    const int bm = blockIdx.x * 128;
    const int tid = threadIdx.x;
    const int lane = tid & 63;
    const int wave = tid >> 6;
    const int wm = (wave & 1) * 64;
    const int wn = (wave >> 1) * 32;

    __shared__ __align__(16) unsigned short As[128 * 32];  // 8 KB
    __shared__ __align__(16) unsigned short Bs[64 * 32];   // 4 KB

    f32x4 acc[4][2] = {};

    const int srow = tid >> 2;          // 0..63
    const int sk = (tid & 3) * 8;

    const unsigned short* ga0 = A + (size_t)(bm + srow) * 512 + sk;
    const unsigned short* ga1 = A + (size_t)(bm + srow + 64) * 512 + sk;
    const unsigned short* gb  = W + (size_t)srow * 512 + sk;

    unsigned short* lA0 = As + wave * 512;
    unsigned short* lA1 = As + 2048 + wave * 512;
    unsigned short* lB  = Bs + wave * 512;

    for (int kb = 0; kb < 16; kb++) {
        const int k0 = kb * 32;
        __builtin_amdgcn_global_load_lds(
            (const __attribute__((address_space(1))) unsigned int*)(ga0 + k0),
            (__attribute__((address_space(3))) unsigned int*)lA0, 16, 0, 0);
        __builtin_amdgcn_global_load_lds(
            (const __attribute__((address_space(1))) unsigned int*)(ga1 + k0),
            (__attribute__((address_space(3))) unsigned int*)lA1, 16, 0, 0);
        __builtin_amdgcn_global_load_lds(
            (const __attribute__((address_space(1))) unsigned int*)(gb + k0),
            (__attribute__((address_space(3))) unsigned int*)lB, 16, 0, 0);
        __syncthreads();

        short8 af[4], bfr[2];
        #pragma unroll
        for (int i = 0; i < 4; i++)
            af[i]  = *(const short8*)&As[(wm + i * 16 + (lane & 15)) * 32 + (lane >> 4) * 8];
        #pragma unroll
        for (int j = 0; j < 2; j++)
            bfr[j] = *(const short8*)&Bs[(wn + j * 16 + (lane & 15)) * 32 + (lane >> 4) * 8];
        #pragma unroll
        for (int i = 0; i < 4; i++)
            #pragma unroll
            for (int j = 0; j < 2; j++)
                acc[i][j] = __builtin_amdgcn_mfma_f32_16x16x32_bf16(af[i], bfr[j], acc[i][j], 0, 0, 0);
        __syncthreads();
    }

    const int cn = lane & 15;
    const int cr = (lane >> 4) * 4;
    #pragma unroll
    for (int j = 0; j < 2; j++) {
        const int n = wn + j * 16 + cn;
        if (n < KK) {
            const float bv = bias[n];
            #pragma unroll
            for (int i = 0; i < 4; i++) {
                #pragma unroll
                for (int r = 0; r < 4; r++) {
                    const int m = bm + wm + i * 16 + cr + r;
                    em[(size_t)m * KK + n] = acc[i][j][r] + bv;
                }
            }
        }
    }
}

// ---------- LSTM recurrence: grid (32 batch-pairs, 2 dirs), 1024 threads ----------
// R12 = R10's 2-batch L2 amortization + R2's 16-wave issue structure.
// Post-mortems: R8 (128 blk x 8 waves, 1 batch) ran at 34 TB/s = L2 aggregate
// ceiling (245us). R10 (64 blk x 8 waves, 2 batches) halved traffic but also
// halved TLP -> latency-bound at 9 TB/s (449us). This round: 64 blocks x
// 16 waves, 2 batches -> traffic halved AND 4 waves/SIMD of latency hiding.
// tid = kq*256+u (4-way K split); each thread streams 16 weight words/step,
// dots each against BOTH batches' h dword. Epilogue on kq0 waves only
// (R10 lesson: all-wave epilogue wastes issue).
__global__ __launch_bounds__(1024, 4) void lstm_kernel(
    const unsigned short* __restrict__ zin_f, const unsigned short* __restrict__ zin_b,
    const int* __restrict__ WQf, const int* __restrict__ WQb,
    const float* __restrict__ Sf, const float* __restrict__ Sb,
    unsigned short* __restrict__ h_out)  // (T,B,512) bf16; fwd cols [0:256), bwd [256:512)
{
    const int dir = blockIdx.y;
    const unsigned short* zin = dir ? zin_b : zin_f;
    const int*   WQ = dir ? WQb : WQf;
    const float* S  = dir ? Sb  : Sf;
    const int off = dir ? HH : 0;

    const int b0 = blockIdx.x * 2;      // this block's two batches
    const int b1 = b0 + 1;
    const int tid = threadIdx.x;
    const int u  = tid & 255;
    const int kq = tid >> 8;            // K quarter, wave-uniform (waves kq*4..kq*4+3)

    __shared__ __align__(16) unsigned char hq8[2][2][HH]; // [buf][batch][unit] 1 KB
    __shared__ int4 red[3][2][HH];                         // [kq-1][batch][unit] 24 KB

    const int4* wp = (const int4*)WQ + kq * 16 * 256 + u;

    float4 sc = make_float4(0.f, 0.f, 0.f, 0.f);
    if (kq == 0) {
        sc = *(const float4*)(S + 4 * u);
        const float inv127 = 1.0f / 127.0f;
        sc.x *= inv127; sc.y *= inv127; sc.z *= inv127; sc.w *= inv127;
    }
    float c0 = 0.0f, c1 = 0.0f;
    int cur = 0;
    if (tid < 256) ((unsigned int*)hq8)[tid] = 0u;   // zero both buffers (1 KB)
    __syncthreads();

    // prefetch z for step 0 (kq0 lanes only), both batches
    ushort4 zv0 = make_ushort4(0, 0, 0, 0), zv1 = zv0;
    if (kq == 0) {
        const int tt0 = dir ? (TT - 1) : 0;
        zv0 = *(const ushort4*)(zin + (tt0 * BB + b0) * FH + 4 * u);
        zv1 = *(const ushort4*)(zin + (tt0 * BB + b1) * FH + 4 * u);
    }

    for (int ts = 0; ts < TT; ts++) {
        const int tt = dir ? (TT - 1 - ts) : ts;
        const int row = tt * BB;

        // issue NEXT step's zin loads now; consumed next iteration
        ushort4 zv0_n = make_ushort4(0, 0, 0, 0), zv1_n = zv0_n;
        if (kq == 0) {
            const int ts_n = (ts + 1 < TT) ? (ts + 1) : ts;
            const int tt_n = dir ? (TT - 1 - ts_n) : ts_n;
            zv0_n = *(const ushort4*)(zin + (tt_n * BB + b0) * FH + 4 * u);
            zv1_n = *(const ushort4*)(zin + (tt_n * BB + b1) * FH + 4 * u);
        }

        // h quarters for both batches: 4x ds_read_b128 each, wave-uniform addr
        const int4* hv0 = (const int4*)&hq8[cur][0][kq * 64];
        const int4* hv1 = (const int4*)&hq8[cur][1][kq * 64];
        const int4 hA0 = hv0[0], hB0 = hv0[1], hC0 = hv0[2], hD0 = hv0[3];
        const int4 hA1 = hv1[0], hB1 = hv1[1], hC1 = hv1[2], hD1 = hv1[3];

        int a0 = 0, a1 = 0, a2 = 0, a3 = 0;     // batch b0 gates
        int d0 = 0, d1 = 0, d2 = 0, d3 = 0;     // batch b1 gates
        {
            const int4 wv = wp[0 * 256];
            lstm_dot(hA0.x, wv, a0, a1, a2, a3); lstm_dot(hA1.x, wv, d0, d1, d2, d3);
        }
        {
            const int4 wv = wp[1 * 256];
            lstm_dot(hA0.y, wv, a0, a1, a2, a3); lstm_dot(hA1.y, wv, d0, d1, d2, d3);
        }
        {
            const int4 wv = wp[2 * 256];
            lstm_dot(hA0.z, wv, a0, a1, a2, a3); lstm_dot(hA1.z, wv, d0, d1, d2, d3);
        }
        {
            const int4 wv = wp[3 * 256];
            lstm_dot(hA0.w, wv, a0, a1, a2, a3); lstm_dot(hA1.w, wv, d0, d1, d2, d3);
        }
        {
            const int4 wv = wp[4 * 256];
            lstm_dot(hB0.x, wv, a0, a1, a2, a3); lstm_dot(hB1.x, wv, d0, d1, d2, d3);
        }
        {
            const int4 wv = wp[5 * 256];
            lstm_dot(hB0.y, wv, a0, a1, a2, a3); lstm_dot(hB1.y, wv, d0, d1, d2, d3);
        }
        {
            const int4 wv = wp[6 * 256];
            lstm_dot(hB0.z, wv, a0, a1, a2, a3); lstm_dot(hB1.z, wv, d0, d1, d2, d3);
        }
        {
            const int4 wv = wp[7 * 256];
            lstm_dot(hB0.w, wv, a0, a1, a2, a3); lstm_dot(hB1.w, wv, d0, d1, d2, d3);
        }
        {
            const int4 wv = wp[8 * 256];
            lstm_dot(hC0.x, wv, a0, a1, a2, a3); lstm_dot(hC1.x, wv, d0, d1, d2, d3);
        }
        {
            const int4 wv = wp[9 * 256];
            lstm_dot(hC0.y, wv, a0, a1, a2, a3); lstm_dot(hC1.y, wv, d0, d1, d2, d3);
        }
        {
            const int4 wv = wp[10 * 256];
            lstm_dot(hC0.z, wv, a0, a1, a2, a3); lstm_dot(hC1.z, wv, d0, d1, d2, d3);
        }
        {
            const int4 wv = wp[11 * 256];
            lstm_dot(hC0.w, wv, a0, a1, a2, a3); lstm_dot(hC1.w, wv, d0, d1, d2, d3);
        }
        {
            const int4 wv = wp[12 * 256];
            lstm_dot(hD0.x, wv, a0, a1, a2, a3); lstm_dot(hD1.x, wv, d0, d1, d2, d3);
        }
        {
            const int4 wv = wp[13 * 256];
            lstm_dot(hD0.y, wv, a0, a1, a2, a3); lstm_dot(hD1.y, wv, d0, d1, d2, d3);
        }
        {
            const int4 wv = wp[14 * 256];
            lstm_dot(hD0.z, wv, a0, a1, a2, a3); lstm_dot(hD1.z, wv, d0, d1, d2, d3);
        }
        {
            const int4 wv = wp[15 * 256];
            lstm_dot(hD0.w, wv, a0, a1, a2, a3); lstm_dot(hD1.w, wv, d0, d1, d2, d3);
        }

        if (kq) {
            red[kq - 1][0][u] = make_int4(a0, a1, a2, a3);
            red[kq - 1][1][u] = make_int4(d0, d1, d2, d3);
        }
        barrier_lgkm();

        if (kq == 0) {
            const int4 r00 = red[0][0][u], r10 = red[1][0][u], r20 = red[2][0][u];
            const int4 r01 = red[0][1][u], r11 = red[1][1][u], r21 = red[2][1][u];
            const int A0 = a0 + r00.x + r10.x + r20.x;
            const int A1 = a1 + r00.y + r10.y + r20.y;
            const int A2 = a2 + r00.z + r10.z + r20.z;
            const int A3 = a3 + r00.w + r10.w + r20.w;
            const int D0 = d0 + r01.x + r11.x + r21.x;
            const int D1 = d1 + r01.y + r11.y + r21.y;
            const int D2 = d2 + r01.z + r11.z + r21.z;
            const int D3 = d3 + r01.w + r11.w + r21.w;
            // batch b0
            const float zi0 = (float)A0 * sc.x + bf2f(zv0.x);
            const float zf0 = (float)A1 * sc.y + bf2f(zv0.y);
            const float zg0 = (float)A2 * sc.z + bf2f(zv0.z);
            const float zo0 = (float)A3 * sc.w + bf2f(zv0.w);
            // batch b1 (independent chain -> interleaves with b0 for ILP)
            const float zi1 = (float)D0 * sc.x + bf2f(zv1.x);
            const float zf1 = (float)D1 * sc.y + bf2f(zv1.y);
            const float zg1 = (float)D2 * sc.z + bf2f(zv1.z);
            const float zo1 = (float)D3 * sc.w + bf2f(zv1.w);
            const float cc0 = sigm(zf0) * c0 + sigm(zi0) * tanh_f(zg0);
            const float cc1 = sigm(zf1) * c1 + sigm(zi1) * tanh_f(zg1);
            c0 = cc0; c1 = cc1;
            const float hh0 = sigm(zo0) * tanh_f(cc0);
            const float hh1 = sigm(zo1) * tanh_f(cc1);
            hq8[cur ^ 1][0][u] = (unsigned char)((int)rintf(hh0 * 127.0f));
            hq8[cur ^ 1][1][u] = (unsigned char)((int)rintf(hh1 * 127.0f));
            h_out[(row + b0) * (2 * HH) + off + u] = f2bf(hh0);
            h_out[(row + b1) * (2 * HH) + off + u] = f2bf(hh1);
        }
        barrier_lgkm();
        cur ^= 1;
        zv0 = zv0_n; zv1 = zv1_n;
    }
}

// ---------- CRF: one block (1 wave) per batch ----------
__global__ __launch_bounds__(64) void crf_kernel(
    const int* __restrict__ text, const int* __restrict__ sbj,
    const float* __restrict__ em,
    const float* __restrict__ start_t, const float* __restrict__ end_t,
    const float* __restrict__ trans, float* __restrict__ accum)
{
    const int b = blockIdx.x;
    const int tid = threadIdx.x;
    __shared__ float tr[KK * KK];
    __shared__ float sc[2][KK];
    for (int x = tid; x < KK * KK; x += 64) tr[x] = trans[x];

    int cnt = 0;
    for (int t = tid; t < TT; t += 64) cnt += (text[b * TT + t] != 0) ? 1 : 0;
    #pragma unroll
    for (int s = 32; s > 0; s >>= 1) cnt += __shfl_down(cnt, s, 64);
    const int len = __shfl(cnt, 0, 64);

    __syncthreads();

    float part = 0.f;
    for (int t = tid; t < TT; t += 64) {
        if (t >= 1 && t < len) {
            const int tg = sbj[b * TT + t];
            const int tp = sbj[b * TT + t - 1];
            part += em[(t * BB + b) * KK + tg] + tr[tp * KK + tg];
        }
    }
    #pragma unroll
    for (int s = 32; s > 0; s >>= 1) part += __shfl_down(part, s, 64);

    // cache this thread's trans column: tc[k1] = tr[k1][tid]  (t-invariant)
    float tc[KK];
    #pragma unroll
    for (int k1 = 0; k1 < KK; k1++) tc[k1] = (tid < KK) ? tr[k1 * KK + tid] : 0.f;

    if (tid < KK) sc[0][tid] = start_t[tid] + em[b * KK + tid];
    __syncthreads();
    int cur = 0;
    // prefetch em row for t=1
    float ev = (tid < KK && len > 1) ? em[(BB + b) * KK + tid] : 0.f;
    for (int t = 1; t < len; t++) {
        // prefetch next step's em row (consumed next iteration)
        const float ev_n = (tid < KK && t + 1 < len) ? em[((t + 1) * BB + b) * KK + tid] : 0.f;
        float nv = 0.f;
        if (tid < KK) {
            float v[KK];
            float mx = -1e30f;
            #pragma unroll
            for (int k1 = 0; k1 < KK; k1++) {
                v[k1] = sc[cur][k1] + tc[k1];
                mx = fmaxf(mx, v[k1]);
            }
            float s = 0.f;
            #pragma unroll
            for (int k1 = 0; k1 < KK; k1++)
                s += __expf(v[k1] - mx);
            nv = mx + __logf(s) + ev;
        }
        if (tid < KK) sc[cur ^ 1][tid] = nv;
        barrier_lgkm();
        cur ^= 1;
        ev = ev_n;
    }

    if (tid == 0) {
        const int tg0 = sbj[b * TT];
        const int tgl = sbj[b * TT + len - 1];
        const float num = start_t[tg0] + em[b * KK + tg0] + part + end_t[tgl];
        float mx = -1e30f;
        for (int k = 0; k < KK; k++) mx = fmaxf(mx, sc[cur][k] + end_t[k]);
        float s = 0.f;
        for (int k = 0; k < KK; k++) s += __expf(sc[cur][k] + end_t[k] - mx);
        const float logZ = mx + __logf(s);
        atomicAdd(&accum[0], num - logZ);
        atomicAdd(&accum[1], (float)len);
    }
}

__global__ void init_kernel(float* __restrict__ accum) {
    if (threadIdx.x < 2) accum[threadIdx.x] = 0.0f;
}
__global__ void final_kernel(const float* __restrict__ accum, float* __restrict__ out) {
    out[0] = -(accum[0] / accum[1]);
}

// ---------- launch ----------
extern "C" void kernel_launch(void* const* d_in, const int* in_sizes, int n_in,
                              void* d_out, int out_size, void* d_ws, size_t ws_size,
                              hipStream_t stream)
{
    (void)in_sizes; (void)n_in; (void)out_size; (void)ws_size;
    const int*   text  = (const int*)d_in[0];
    const int*   sbj   = (const int*)d_in[1];
    const float* emb   = (const float*)d_in[2];
    const float* Wih0f = (const float*)d_in[3];
    const float* Whh0f = (const float*)d_in[4];
    const float* b0f   = (const float*)d_in[5];
    const float* Wih0b = (const float*)d_in[6];
    const float* Whh0b = (const float*)d_in[7];
    const float* b0b   = (const float*)d_in[8];
    const float* Wih1f = (const float*)d_in[9];
    const float* Whh1f = (const float*)d_in[10];
    const float* b1f   = (const float*)d_in[11];
    const float* Wih1b = (const float*)d_in[12];
    const float* Whh1b = (const float*)d_in[13];
    const float* b1b   = (const float*)d_in[14];
    const float* Wsbj  = (const float*)d_in[15];
    const float* bsbj  = (const float*)d_in[16];
    const float* start_t = (const float*)d_in[17];
    const float* end_t   = (const float*)d_in[18];
    const float* trans   = (const float*)d_in[19];

    // workspace map (bytes), max ~102.84 MB. Overlaps (stream-ordered lifetimes):
    char* ws = (char*)d_ws;
    unsigned short* zf   = (unsigned short*)(ws + 0);           // 32 MiB
    unsigned short* zb   = (unsigned short*)(ws + 33554432);    // 32 MiB
    unsigned short* h0   = (unsigned short*)(ws + 67108864);    // 16 MiB
    unsigned short* h1   = (unsigned short*)(ws + 83886080);    // 16 MiB
    unsigned short* Wb0f = (unsigned short*)(ws + 67108864);    // 1024x320 bf16
    unsigned short* Wb0b = (unsigned short*)(ws + 67764224);
    unsigned short* Abf  = (unsigned short*)(ws + 83886080);    // 16384x320 bf16 (10 MiB)
    unsigned short* Wb1f = (unsigned short*)(ws + 94371840);    // 1024x512 bf16
    unsigned short* Wb1b = (unsigned short*)(ws + 95420416);
    unsigned int*   WQ   = (unsigned int*)(ws + 100663296);     // 4 x 256 KiB int8 weights
    float*          Sq   = (float*)(ws + 101711872);            // 4 x 4 KiB scales
    unsigned short* WsbjB = (unsigned short*)(ws + 102760448);  // 64x512 bf16 (64 KiB)
    float*          acc  = (float*)(ws + 102836224);            // 8 B
    float*           em  = (float*)(ws + 0);                    // 2.4 MiB (over zf)
    float* out = (float*)d_out;

    const int* WQ0f = (const int*)(WQ + 0 * 65536);
    const int* WQ0b = (const int*)(WQ + 1 * 65536);
    const int* WQ1f = (const int*)(WQ + 2 * 65536);
    const int* WQ1b = (const int*)(WQ + 3 * 65536);
    const float* S0f = Sq + 0 * 1024;
    const float* S0b = Sq + 1 * 1024;
    const float* S1f = Sq + 2 * 1024;
    const float* S1b = Sq + 3 * 1024;

    init_kernel<<<1, 64, 0, stream>>>(acc);
    conv_quant<<<dim3(4096), 64, 0, stream>>>(Whh0f, Whh0b, Whh1f, Whh1b, Sq, WQ);
    conv_wsbj_bf<<<dim3(128), 256, 0, stream>>>(Wsbj, WsbjB);
    conv_gather<<<dim3(MTOT), 320, 0, stream>>>(text, emb, Abf);
    conv_w4<<<dim3(2048, 4), 256, 0, stream>>>(Wih0f, Wih0b, Wih1f, Wih1b,
                                               Wb0f, Wb0b, Wb1f, Wb1b);

    // layer 0 input projection (MFMA), f+b in one dispatch
    gemm_mfma2<<<dim3(128, 8, 2), 256, 0, stream>>>(Abf, Wb0f, Wb0b, b0f, b0b, zf, zb, KP0);
    lstm_kernel<<<dim3(BB / 2, 2), 1024, 0, stream>>>(zf, zb, WQ0f, WQ0b, S0f, S0b, h0);
    // layer 1 input projection (MFMA), f+b in one dispatch
    gemm_mfma2<<<dim3(128, 8, 2), 256, 0, stream>>>(h0, Wb1f, Wb1b, b1f, b1b, zf, zb, 512);
    lstm_kernel<<<dim3(BB / 2, 2), 1024, 0, stream>>>(zf, zb, WQ1f, WQ1b, S1f, S1b, h1);

    gemm_em<<<dim3(128), 256, 0, stream>>>(h1, WsbjB, bsbj, em);
    crf_kernel<<<BB, 64, 0, stream>>>(text, sbj, em, start_t, end_t, trans, acc);
    final_kernel<<<1, 1, 0, stream>>>(acc, out);
}

// Round 13
// 1209.819 us; speedup vs baseline: 1.1920x; 1.1920x over previous
//
#include <hip/hip_runtime.h>
#include <math.h>

// Problem constants
#define TT 256      // sequence length
#define BB 64       // batch
#define DD 300      // embedding dim
#define KP0 320     // layer-0 K padded to multiple of 32
#define HH 256      // hidden
#define KK 37       // CRF states
#define FH 1024     // 4*H
#define MTOT (TT*BB) // 16384 rows, time-major r = t*64 + b

typedef __attribute__((ext_vector_type(8))) short short8;  // 8 bf16 (4 VGPR) MFMA A/B frag
typedef __attribute__((ext_vector_type(4))) float f32x4;   // MFMA C/D frag

// ---------- bf16 helpers ----------
__device__ __forceinline__ float bf2f(unsigned short u) {
    union { float f; unsigned int i; } v; v.i = ((unsigned int)u) << 16; return v.f;
}
__device__ __forceinline__ unsigned short f2bf(float f) {
    union { float f; unsigned int i; } v; v.f = f;
    unsigned int i = v.i;
    unsigned int r = (i + 0x7FFFu + ((i >> 16) & 1u)) >> 16; // RNE
    return (unsigned short)r;
}
__device__ __forceinline__ float sigm(float x)   { return 1.0f / (1.0f + __expf(-x)); }
__device__ __forceinline__ float tanh_f(float x) { return 2.0f / (1.0f + __expf(-2.0f * x)) - 1.0f; }

// signed byte extract (compiler -> v_bfe_i32)
__device__ __forceinline__ int sb0(int w) { return (w << 24) >> 24; }
__device__ __forceinline__ int sb1(int w) { return (w << 16) >> 24; }
__device__ __forceinline__ int sb2(int w) { return (w <<  8) >> 24; }
__device__ __forceinline__ int sb3(int w) { return  w        >> 24; }

#if defined(__has_builtin)
#if __has_builtin(__builtin_amdgcn_sdot4)
#define HAVE_SDOT4 1
#endif
#endif

// 4x int8 dot product: c += dot(a.bytes, b.bytes)
__device__ __forceinline__ int dot4i8(int a, int b, int c) {
#ifdef HAVE_SDOT4
    return __builtin_amdgcn_sdot4(a, b, c, false);
#else
    return c + sb0(a) * sb0(b) + sb1(a) * sb1(b) + sb2(a) * sb2(b) + sb3(a) * sb3(b);
#endif
}

// barrier that waits only on LDS ops (lgkmcnt), NOT on global loads/stores.
__device__ __forceinline__ void barrier_lgkm() {
    asm volatile("s_waitcnt lgkmcnt(0)\n\ts_barrier" ::: "memory");
}

// permute gate-major col (g*256+unit) -> interleaved (unit*4+g)
__device__ __forceinline__ int perm_col(int nn) { return ((nn & 255) << 2) | (nn >> 8); }

// read one stashed weight dword back from its AGPR, then 4-gate sdot4.
// twx.. are macro-local; hwd/j are tokens (no member access on params).
#define LSTM_DOT_AGPR(hwd, j) do { \
        int twx, twy, twz, tww; \
        asm volatile("v_accvgpr_read_b32 %0, %1" : "=v"(twx) : "a"(wa[4*(j)+0])); \
        asm volatile("v_accvgpr_read_b32 %0, %1" : "=v"(twy) : "a"(wa[4*(j)+1])); \
        asm volatile("v_accvgpr_read_b32 %0, %1" : "=v"(twz) : "a"(wa[4*(j)+2])); \
        asm volatile("v_accvgpr_read_b32 %0, %1" : "=v"(tww) : "a"(wa[4*(j)+3])); \
        a0 = dot4i8((hwd), twx, a0); \
        a1 = dot4i8((hwd), twy, a1); \
        a2 = dot4i8((hwd), twz, a2); \
        a3 = dot4i8((hwd), tww, a3); \
    } while (0)

// ---------- prep: FUSED per-row scale + int8 quantize of Whh ----------
__global__ __launch_bounds__(64) void conv_quant(
    const float* __restrict__ w0f, const float* __restrict__ w0b,
    const float* __restrict__ w1f, const float* __restrict__ w1b,
    float* __restrict__ S, unsigned int* __restrict__ WQ)
{
    const int m = blockIdx.x >> 10;
    const int r = blockIdx.x & 1023;          // r = g*256 + u
    const float* W = m == 0 ? w0f : m == 1 ? w0b : m == 2 ? w1f : w1b;
    const int t = threadIdx.x;
    const float4 wv = *(const float4*)(W + r * HH + t * 4);  // this thread's 4 k's
    float mx = fmaxf(fmaxf(fabsf(wv.x), fabsf(wv.y)), fmaxf(fabsf(wv.z), fabsf(wv.w)));
    #pragma unroll
    for (int s = 32; s > 0; s >>= 1) mx = fmaxf(mx, __shfl_down(mx, s, 64));
    const float mxall = __shfl(mx, 0, 64);
    const float s = fmaxf(mxall, 1e-20f) / 127.0f;
    const int g = r >> 8, u = r & 255;
    if (t == 0) S[m * 1024 + u * 4 + g] = s;
    int q0 = (int)rintf(wv.x / s), q1 = (int)rintf(wv.y / s);
    int q2 = (int)rintf(wv.z / s), q3 = (int)rintf(wv.w / s);
    q0 = max(-127, min(127, q0)); q1 = max(-127, min(127, q1));
    q2 = max(-127, min(127, q2)); q3 = max(-127, min(127, q3));
    WQ[m * 65536 + (t * 256 + u) * 4 + g] =
        (unsigned int)(q0 & 0xff) | ((unsigned int)(q1 & 0xff) << 8) |
        ((unsigned int)(q2 & 0xff) << 16) | ((unsigned int)(q3 & 0xff) << 24);
}

// ---------- prep: Wsbj f32 (37x512) -> bf16 padded (64x512), rows>=37 zero ----------
__global__ __launch_bounds__(256) void conv_wsbj_bf(
    const float* __restrict__ Wsbj, unsigned short* __restrict__ WB)
{
    const int idx = blockIdx.x * 256 + threadIdx.x;   // 0 .. 64*512-1
    if (idx >= 64 * 512) return;
    const int r = idx >> 9, cidx = idx & 511;
    WB[idx] = (r < KK) ? f2bf(Wsbj[r * 512 + cidx]) : (unsigned short)0;
}

// ---------- prep: gather embedding rows -> Abf bf16 [16384][320] (zero-pad k>=300) ----------
__global__ __launch_bounds__(320) void conv_gather(
    const int* __restrict__ text, const float* __restrict__ emb,
    unsigned short* __restrict__ Abf)
{
    const int r = blockIdx.x;
    const int k = threadIdx.x;
    const int t = r >> 6, b = r & 63;
    const int idx = text[b * TT + t];
    Abf[r * KP0 + k] = (k < DD) ? f2bf(emb[(size_t)idx * DD + k]) : (unsigned short)0;
}

// ---------- prep: 4x W f32 -> bf16 zero-padded, merged into one dispatch ----------
__global__ __launch_bounds__(256) void conv_w4(
    const float* __restrict__ s0, const float* __restrict__ s1,
    const float* __restrict__ s2, const float* __restrict__ s3,
    unsigned short* __restrict__ d0, unsigned short* __restrict__ d1,
    unsigned short* __restrict__ d2, unsigned short* __restrict__ d3)
{
    const int z = blockIdx.y;
    const float* src = z == 0 ? s0 : z == 1 ? s1 : z == 2 ? s2 : s3;
    unsigned short* dst = z == 0 ? d0 : z == 1 ? d1 : z == 2 ? d2 : d3;
    const int kin   = z < 2 ? DD  : 512;
    const int kout  = z < 2 ? KP0 : 512;
    const int total = 1024 * kout;
    const int idx = blockIdx.x * 256 + threadIdx.x;
    if (idx >= total) return;
    const int rr = idx / kout, k = idx - rr * kout;
    dst[idx] = (k < kin) ? f2bf(src[rr * kin + k]) : (unsigned short)0;
}

// ---------- MFMA GEMM (f+b merged on blockIdx.z): out_z = A @ W_z^T + bias_z ----------
__global__ __launch_bounds__(256) void gemm_mfma2(
    const unsigned short* __restrict__ A,
    const unsigned short* __restrict__ Wf,
    const unsigned short* __restrict__ Wb,
    const float* __restrict__ biasf,
    const float* __restrict__ biasb,
    unsigned short* __restrict__ outf,
    unsigned short* __restrict__ outb,
    int lda)
{
    const unsigned short* W = blockIdx.z ? Wb : Wf;
    const float* bias        = blockIdx.z ? biasb : biasf;
    unsigned short* out      = blockIdx.z ? outb : outf;

    const int bm = blockIdx.x * 128;
    const int bn = blockIdx.y * 128;
    const int tid = threadIdx.x;
    const int lane = tid & 63;
    const int wave = tid >> 6;
    const int wm = (wave & 1) * 64;
    const int wn = (wave >> 1) * 64;

    __shared__ __align__(16) unsigned short As[128 * 32];  // [row][k] 8 KB
    __shared__ __align__(16) unsigned short Bs[128 * 32];  // [wrow][k] 8 KB

    f32x4 acc[4][4] = {};

    const int srow = tid >> 2;          // 0..63
    const int sk = (tid & 3) * 8;       // k element offset (16 B granules)

    const unsigned short* ga0 = A + (size_t)(bm + srow) * lda + sk;
    const unsigned short* ga1 = A + (size_t)(bm + srow + 64) * lda + sk;
    const unsigned short* gb0 = W + (size_t)(bn + srow) * lda + sk;
    const unsigned short* gb1 = W + (size_t)(bn + srow + 64) * lda + sk;

    unsigned short* lA0 = As + wave * 512;
    unsigned short* lA1 = As + 2048 + wave * 512;
    unsigned short* lB0 = Bs + wave * 512;
    unsigned short* lB1 = Bs + 2048 + wave * 512;

    const int kiters = lda >> 5;
    for (int kb = 0; kb < kiters; kb++) {
        const int k0 = kb * 32;
        __builtin_amdgcn_global_load_lds(
            (const __attribute__((address_space(1))) unsigned int*)(ga0 + k0),
            (__attribute__((address_space(3))) unsigned int*)lA0, 16, 0, 0);
        __builtin_amdgcn_global_load_lds(
            (const __attribute__((address_space(1))) unsigned int*)(ga1 + k0),
            (__attribute__((address_space(3))) unsigned int*)lA1, 16, 0, 0);
        __builtin_amdgcn_global_load_lds(
            (const __attribute__((address_space(1))) unsigned int*)(gb0 + k0),
            (__attribute__((address_space(3))) unsigned int*)lB0, 16, 0, 0);
        __builtin_amdgcn_global_load_lds(
            (const __attribute__((address_space(1))) unsigned int*)(gb1 + k0),
            (__attribute__((address_space(3))) unsigned int*)lB1, 16, 0, 0);
        __syncthreads();

        short8 af[4], bfr[4];
        #pragma unroll
        for (int i = 0; i < 4; i++) {
            af[i]  = *(const short8*)&As[(wm + i * 16 + (lane & 15)) * 32 + (lane >> 4) * 8];
            bfr[i] = *(const short8*)&Bs[(wn + i * 16 + (lane & 15)) * 32 + (lane >> 4) * 8];
        }
        #pragma unroll
        for (int i = 0; i < 4; i++)
            #pragma unroll
            for (int j = 0; j < 4; j++)
                acc[i][j] = __builtin_amdgcn_mfma_f32_16x16x32_bf16(af[i], bfr[j], acc[i][j], 0, 0, 0);
        __syncthreads();
    }

    // C/D: col = lane&15, row = (lane>>4)*4 + reg  [measured m89/m91]
    const int cn = lane & 15;
    const int cr = (lane >> 4) * 4;
    #pragma unroll
    for (int j = 0; j < 4; j++) {
        const int n = bn + wn + j * 16 + cn;
        const float bv = bias[n];
        const int pc = perm_col(n);
        #pragma unroll
        for (int i = 0; i < 4; i++) {
            #pragma unroll
            for (int r = 0; r < 4; r++) {
                const int m = bm + wm + i * 16 + cr + r;
                out[(size_t)m * FH + pc] = f2bf(acc[i][j][r] + bv);
            }
        }
    }
}

// ---------- Emission GEMM: em = h1(16384x512 bf16) @ WsbjB(64x512 bf16)^T + bias, f32 out ----------
__global__ __launch_bounds__(256) void gemm_em(
    const unsigned short* __restrict__ A,
    const unsigned short* __restrict__ W,
    const float* __restrict__ bias,
    float* __restrict__ em)
{
    const int bm = blockIdx.x * 128;
    const int tid = threadIdx.x;
    const int lane = tid & 63;
    const int wave = tid >> 6;
    const int wm = (wave & 1) * 64;
    const int wn = (wave >> 1) * 32;

    __shared__ __align__(16) unsigned short As[128 * 32];  // 8 KB
    __shared__ __align__(16) unsigned short Bs[64 * 32];   // 4 KB

    f32x4 acc[4][2] = {};

    const int srow = tid >> 2;          // 0..63
    const int sk = (tid & 3) * 8;

    const unsigned short* ga0 = A + (size_t)(bm + srow) * 512 + sk;
    const unsigned short* ga1 = A + (size_t)(bm + srow + 64) * 512 + sk;
    const unsigned short* gb  = W + (size_t)srow * 512 + sk;

    unsigned short* lA0 = As + wave * 512;
    unsigned short* lA1 = As + 2048 + wave * 512;
    unsigned short* lB  = Bs + wave * 512;

    for (int kb = 0; kb < 16; kb++) {
        const int k0 = kb * 32;
        __builtin_amdgcn_global_load_lds(
            (const __attribute__((address_space(1))) unsigned int*)(ga0 + k0),
            (__attribute__((address_space(3))) unsigned int*)lA0, 16, 0, 0);
        __builtin_amdgcn_global_load_lds(
            (const __attribute__((address_space(1))) unsigned int*)(ga1 + k0),
            (__attribute__((address_space(3))) unsigned int*)lA1, 16, 0, 0);
        __builtin_amdgcn_global_load_lds(
            (const __attribute__((address_space(1))) unsigned int*)(gb + k0),
            (__attribute__((address_space(3))) unsigned int*)lB, 16, 0, 0);
        __syncthreads();

        short8 af[4], bfr[2];
        #pragma unroll
        for (int i = 0; i < 4; i++)
            af[i]  = *(const short8*)&As[(wm + i * 16 + (lane & 15)) * 32 + (lane >> 4) * 8];
        #pragma unroll
        for (int j = 0; j < 2; j++)
            bfr[j] = *(const short8*)&Bs[(wn + j * 16 + (lane & 15)) * 32 + (lane >> 4) * 8];
        #pragma unroll
        for (int i = 0; i < 4; i++)
            #pragma unroll
            for (int j = 0; j < 2; j++)
                acc[i][j] = __builtin_amdgcn_mfma_f32_16x16x32_bf16(af[i], bfr[j], acc[i][j], 0, 0, 0);
        __syncthreads();
    }

    const int cn = lane & 15;
    const int cr = (lane >> 4) * 4;
    #pragma unroll
    for (int j = 0; j < 2; j++) {
        const int n = wn + j * 16 + cn;
        if (n < KK) {
            const float bv = bias[n];
            #pragma unroll
            for (int i = 0; i < 4; i++) {
                #pragma unroll
                for (int r = 0; r < 4; r++) {
                    const int m = bm + wm + i * 16 + cr + r;
                    em[(size_t)m * KK + n] = acc[i][j][r] + bv;
                }
            }
        }
    }
}

// ---------- LSTM recurrence: grid (64 batches, 2 dirs), 512 threads ----------
// R13: weights stashed in AGPRs via explicit v_accvgpr asm ("a" constraint).
// Root cause (R2-R12 counters): compiler re-streams the 256 KB weight slab
// from L2 every step (remat / scratch-spill); 128 blocks x 256 KB / 0.956us
// = 34 TB/s == L2 aggregate ceiling. Plain arrays (R8), asm value-pins (R9),
// and batch-merging (R10/R12, starves CUs) all failed. AGPR stash bypasses
// the VGPR allocator heuristics entirely: 128 weight dwords/thread live in
// "a"-class regs (budget 512/wave at 2 waves/SIMD, m08 no-spill <=450);
// volatile accvgpr_read per use prevents remat/hoisting.
// Per-step VALU: 128 reads + 128 sdot4 per thread -> ~1120 cyc/SIMD; no L2
// weight traffic. Expect ~150us (was 245 at the L2 ceiling).
__global__ __launch_bounds__(512, 2) void lstm_kernel(
    const unsigned short* __restrict__ zin_f, const unsigned short* __restrict__ zin_b,
    const int* __restrict__ WQf, const int* __restrict__ WQb,
    const float* __restrict__ Sf, const float* __restrict__ Sb,
    unsigned short* __restrict__ h_out)  // (T,B,512) bf16; fwd cols [0:256), bwd [256:512)
{
    const int dir = blockIdx.y;
    const unsigned short* zin = dir ? zin_b : zin_f;
    const int*   WQ = dir ? WQb : WQf;
    const float* S  = dir ? Sb  : Sf;
    const int off = dir ? HH : 0;

    const int b = blockIdx.x;
    const int tid = threadIdx.x;
    const int u  = tid & 255;
    const int kh = tid >> 8;            // K half, wave-uniform (waves 0-3 / 4-7)

    __shared__ __align__(16) unsigned char hq8[2][HH];  // int8 h, double-buffered
    __shared__ int4 red[HH];                             // kh1 partial sums

    // ---- one-time load of 512 B weights, stashed into 128 AGPRs ----
    const int4* wp = (const int4*)WQ + kh * 32 * 256 + u;
    int wa[128];    // forced into "a"-class regs by the asm constraints below
    #pragma unroll
    for (int j = 0; j < 32; j++) {
        const int4 wv = wp[j * 256];
        asm volatile("v_accvgpr_write_b32 %0, %1" : "=a"(wa[4*j+0]) : "v"(wv.x));
        asm volatile("v_accvgpr_write_b32 %0, %1" : "=a"(wa[4*j+1]) : "v"(wv.y));
        asm volatile("v_accvgpr_write_b32 %0, %1" : "=a"(wa[4*j+2]) : "v"(wv.z));
        asm volatile("v_accvgpr_write_b32 %0, %1" : "=a"(wa[4*j+3]) : "v"(wv.w));
    }

    float4 sc = make_float4(0.f, 0.f, 0.f, 0.f);
    if (kh == 0) {
        sc = *(const float4*)(S + 4 * u);
        const float inv127 = 1.0f / 127.0f;
        sc.x *= inv127; sc.y *= inv127; sc.z *= inv127; sc.w *= inv127;
    }
    float c = 0.0f;
    int cur = 0;
    if (tid < 128) ((unsigned int*)hq8)[tid] = 0u;   // zero both buffers
    __syncthreads();

    // prefetch z for step 0 (kh0 lanes only)
    ushort4 zv = make_ushort4(0, 0, 0, 0);
    if (kh == 0) {
        const int tt0 = dir ? (TT - 1) : 0;
        zv = *(const ushort4*)(zin + (tt0 * BB + b) * FH + 4 * u);
    }

    for (int ts = 0; ts < TT; ts++) {
        const int tt = dir ? (TT - 1 - ts) : ts;
        const int row = tt * BB + b;

        // issue NEXT step's zin load now; consumed next iteration
        ushort4 zv_n = make_ushort4(0, 0, 0, 0);
        if (kh == 0) {
            const int ts_n = (ts + 1 < TT) ? (ts + 1) : ts;
            const int tt_n = dir ? (TT - 1 - ts_n) : ts_n;
            zv_n = *(const ushort4*)(zin + (tt_n * BB + b) * FH + 4 * u);
        }

        // h half for this wave-set: 32 dwords via 8x ds_read_b128, uniform addr
        const int4* hv = (const int4*)&hq8[cur][kh * 128];
        const int4 h0v = hv[0], h1v = hv[1], h2v = hv[2], h3v = hv[3];
        const int4 h4v = hv[4], h5v = hv[5], h6v = hv[6], h7v = hv[7];

        int a0 = 0, a1 = 0, a2 = 0, a3 = 0;
        LSTM_DOT_AGPR(h0v.x,  0); LSTM_DOT_AGPR(h0v.y,  1);
        LSTM_DOT_AGPR(h0v.z,  2); LSTM_DOT_AGPR(h0v.w,  3);
        LSTM_DOT_AGPR(h1v.x,  4); LSTM_DOT_AGPR(h1v.y,  5);
        LSTM_DOT_AGPR(h1v.z,  6); LSTM_DOT_AGPR(h1v.w,  7);
        LSTM_DOT_AGPR(h2v.x,  8); LSTM_DOT_AGPR(h2v.y,  9);
        LSTM_DOT_AGPR(h2v.z, 10); LSTM_DOT_AGPR(h2v.w, 11);
        LSTM_DOT_AGPR(h3v.x, 12); LSTM_DOT_AGPR(h3v.y, 13);
        LSTM_DOT_AGPR(h3v.z, 14); LSTM_DOT_AGPR(h3v.w, 15);
        LSTM_DOT_AGPR(h4v.x, 16); LSTM_DOT_AGPR(h4v.y, 17);
        LSTM_DOT_AGPR(h4v.z, 18); LSTM_DOT_AGPR(h4v.w, 19);
        LSTM_DOT_AGPR(h5v.x, 20); LSTM_DOT_AGPR(h5v.y, 21);
        LSTM_DOT_AGPR(h5v.z, 22); LSTM_DOT_AGPR(h5v.w, 23);
        LSTM_DOT_AGPR(h6v.x, 24); LSTM_DOT_AGPR(h6v.y, 25);
        LSTM_DOT_AGPR(h6v.z, 26); LSTM_DOT_AGPR(h6v.w, 27);
        LSTM_DOT_AGPR(h7v.x, 28); LSTM_DOT_AGPR(h7v.y, 29);
        LSTM_DOT_AGPR(h7v.z, 30); LSTM_DOT_AGPR(h7v.w, 31);

        if (kh) red[u] = make_int4(a0, a1, a2, a3);
        barrier_lgkm();

        if (kh == 0) {
            const int4 r0 = red[u];
            const int A0 = a0 + r0.x;
            const int A1 = a1 + r0.y;
            const int A2 = a2 + r0.z;
            const int A3 = a3 + r0.w;
            const float zi  = (float)A0 * sc.x + bf2f(zv.x);
            const float zf_ = (float)A1 * sc.y + bf2f(zv.y);
            const float zg  = (float)A2 * sc.z + bf2f(zv.z);
            const float zo  = (float)A3 * sc.w + bf2f(zv.w);
            const float cc = sigm(zf_) * c + sigm(zi) * tanh_f(zg);
            c = cc;
            const float hh = sigm(zo) * tanh_f(cc);
            hq8[cur ^ 1][u] = (unsigned char)((int)rintf(hh * 127.0f));
            h_out[row * (2 * HH) + off + u] = f2bf(hh);
        }
        barrier_lgkm();
        cur ^= 1;
        zv = zv_n;
    }
}

// ---------- CRF: one block (1 wave) per batch ----------
__global__ __launch_bounds__(64) void crf_kernel(
    const int* __restrict__ text, const int* __restrict__ sbj,
    const float* __restrict__ em,
    const float* __restrict__ start_t, const float* __restrict__ end_t,
    const float* __restrict__ trans, float* __restrict__ accum)
{
    const int b = blockIdx.x;
    const int tid = threadIdx.x;
    __shared__ float tr[KK * KK];
    __shared__ float sc[2][KK];
    for (int x = tid; x < KK * KK; x += 64) tr[x] = trans[x];

    int cnt = 0;
    for (int t = tid; t < TT; t += 64) cnt += (text[b * TT + t] != 0) ? 1 : 0;
    #pragma unroll
    for (int s = 32; s > 0; s >>= 1) cnt += __shfl_down(cnt, s, 64);
    const int len = __shfl(cnt, 0, 64);

    __syncthreads();

    float part = 0.f;
    for (int t = tid; t < TT; t += 64) {
        if (t >= 1 && t < len) {
            const int tg = sbj[b * TT + t];
            const int tp = sbj[b * TT + t - 1];
            part += em[(t * BB + b) * KK + tg] + tr[tp * KK + tg];
        }
    }
    #pragma unroll
    for (int s = 32; s > 0; s >>= 1) part += __shfl_down(part, s, 64);

    // cache this thread's trans column: tc[k1] = tr[k1][tid]  (t-invariant)
    float tc[KK];
    #pragma unroll
    for (int k1 = 0; k1 < KK; k1++) tc[k1] = (tid < KK) ? tr[k1 * KK + tid] : 0.f;

    if (tid < KK) sc[0][tid] = start_t[tid] + em[b * KK + tid];
    __syncthreads();
    int cur = 0;
    // prefetch em row for t=1
    float ev = (tid < KK && len > 1) ? em[(BB + b) * KK + tid] : 0.f;
    for (int t = 1; t < len; t++) {
        // prefetch next step's em row (consumed next iteration)
        const float ev_n = (tid < KK && t + 1 < len) ? em[((t + 1) * BB + b) * KK + tid] : 0.f;
        float nv = 0.f;
        if (tid < KK) {
            float v[KK];
            float mx = -1e30f;
            #pragma unroll
            for (int k1 = 0; k1 < KK; k1++) {
                v[k1] = sc[cur][k1] + tc[k1];
                mx = fmaxf(mx, v[k1]);
            }
            float s = 0.f;
            #pragma unroll
            for (int k1 = 0; k1 < KK; k1++)
                s += __expf(v[k1] - mx);
            nv = mx + __logf(s) + ev;
        }
        if (tid < KK) sc[cur ^ 1][tid] = nv;
        barrier_lgkm();
        cur ^= 1;
        ev = ev_n;
    }

    if (tid == 0) {
        const int tg0 = sbj[b * TT];
        const int tgl = sbj[b * TT + len - 1];
        const float num = start_t[tg0] + em[b * KK + tg0] + part + end_t[tgl];
        float mx = -1e30f;
        for (int k = 0; k < KK; k++) mx = fmaxf(mx, sc[cur][k] + end_t[k]);
        float s = 0.f;
        for (int k = 0; k < KK; k++) s += __expf(sc[cur][k] + end_t[k] - mx);
        const float logZ = mx + __logf(s);
        atomicAdd(&accum[0], num - logZ);
        atomicAdd(&accum[1], (float)len);
    }
}

__global__ void init_kernel(float* __restrict__ accum) {
    if (threadIdx.x < 2) accum[threadIdx.x] = 0.0f;
}
__global__ void final_kernel(const float* __restrict__ accum, float* __restrict__ out) {
    out[0] = -(accum[0] / accum[1]);
}

// ---------- launch ----------
extern "C" void kernel_launch(void* const* d_in, const int* in_sizes, int n_in,
                              void* d_out, int out_size, void* d_ws, size_t ws_size,
                              hipStream_t stream)
{
    (void)in_sizes; (void)n_in; (void)out_size; (void)ws_size;
    const int*   text  = (const int*)d_in[0];
    const int*   sbj   = (const int*)d_in[1];
    const float* emb   = (const float*)d_in[2];
    const float* Wih0f = (const float*)d_in[3];
    const float* Whh0f = (const float*)d_in[4];
    const float* b0f   = (const float*)d_in[5];
    const float* Wih0b = (const float*)d_in[6];
    const float* Whh0b = (const float*)d_in[7];
    const float* b0b   = (const float*)d_in[8];
    const float* Wih1f = (const float*)d_in[9];
    const float* Whh1f = (const float*)d_in[10];
    const float* b1f   = (const float*)d_in[11];
    const float* Wih1b = (const float*)d_in[12];
    const float* Whh1b = (const float*)d_in[13];
    const float* b1b   = (const float*)d_in[14];
    const float* Wsbj  = (const float*)d_in[15];
    const float* bsbj  = (const float*)d_in[16];
    const float* start_t = (const float*)d_in[17];
    const float* end_t   = (const float*)d_in[18];
    const float* trans   = (const float*)d_in[19];

    // workspace map (bytes), max ~102.84 MB. Overlaps (stream-ordered lifetimes):
    char* ws = (char*)d_ws;
    unsigned short* zf   = (unsigned short*)(ws + 0);           // 32 MiB
    unsigned short* zb   = (unsigned short*)(ws + 33554432);    // 32 MiB
    unsigned short* h0   = (unsigned short*)(ws + 67108864);    // 16 MiB
    unsigned short* h1   = (unsigned short*)(ws + 83886080);    // 16 MiB
    unsigned short* Wb0f = (unsigned short*)(ws + 67108864);    // 1024x320 bf16
    unsigned short* Wb0b = (unsigned short*)(ws + 67764224);
    unsigned short* Abf  = (unsigned short*)(ws + 83886080);    // 16384x320 bf16 (10 MiB)
    unsigned short* Wb1f = (unsigned short*)(ws + 94371840);    // 1024x512 bf16
    unsigned short* Wb1b = (unsigned short*)(ws + 95420416);
    unsigned int*   WQ   = (unsigned int*)(ws + 100663296);     // 4 x 256 KiB int8 weights
    float*          Sq   = (float*)(ws + 101711872);            // 4 x 4 KiB scales
    unsigned short* WsbjB = (unsigned short*)(ws + 102760448);  // 64x512 bf16 (64 KiB)
    float*          acc  = (float*)(ws + 102836224);            // 8 B
    float*           em  = (float*)(ws + 0);                    // 2.4 MiB (over zf)
    float* out = (float*)d_out;

    const int* WQ0f = (const int*)(WQ + 0 * 65536);
    const int* WQ0b = (const int*)(WQ + 1 * 65536);
    const int* WQ1f = (const int*)(WQ + 2 * 65536);
    const int* WQ1b = (const int*)(WQ + 3 * 65536);
    const float* S0f = Sq + 0 * 1024;
    const float* S0b = Sq + 1 * 1024;
    const float* S1f = Sq + 2 * 1024;
    const float* S1b = Sq + 3 * 1024;

    init_kernel<<<1, 64, 0, stream>>>(acc);
    conv_quant<<<dim3(4096), 64, 0, stream>>>(Whh0f, Whh0b, Whh1f, Whh1b, Sq, WQ);
    conv_wsbj_bf<<<dim3(128), 256, 0, stream>>>(Wsbj, WsbjB);
    conv_gather<<<dim3(MTOT), 320, 0, stream>>>(text, emb, Abf);
    conv_w4<<<dim3(2048, 4), 256, 0, stream>>>(Wih0f, Wih0b, Wih1f, Wih1b,
                                               Wb0f, Wb0b, Wb1f, Wb1b);

    // layer 0 input projection (MFMA), f+b in one dispatch
    gemm_mfma2<<<dim3(128, 8, 2), 256, 0, stream>>>(Abf, Wb0f, Wb0b, b0f, b0b, zf, zb, KP0);
    lstm_kernel<<<dim3(BB, 2), 512, 0, stream>>>(zf, zb, WQ0f, WQ0b, S0f, S0b, h0);
    // layer 1 input projection (MFMA), f+b in one dispatch
    gemm_mfma2<<<dim3(128, 8, 2), 256, 0, stream>>>(h0, Wb1f, Wb1b, b1f, b1b, zf, zb, 512);
    lstm_kernel<<<dim3(BB, 2), 512, 0, stream>>>(zf, zb, WQ1f, WQ1b, S1f, S1b, h1);

    gemm_em<<<dim3(128), 256, 0, stream>>>(h1, WsbjB, bsbj, em);
    crf_kernel<<<BB, 64, 0, stream>>>(text, sbj, em, start_t, end_t, trans, acc);
    final_kernel<<<1, 1, 0, stream>>>(acc, out);
}

// Round 14
// 967.867 us; speedup vs baseline: 1.4900x; 1.2500x over previous
//
#include <hip/hip_runtime.h>
#include <math.h>

// Problem constants
#define TT 256      // sequence length
#define BB 64       // batch
#define DD 300      // embedding dim
#define KP0 320     // layer-0 K padded to multiple of 32
#define HH 256      // hidden
#define KK 37       // CRF states
#define FH 1024     // 4*H
#define MTOT (TT*BB) // 16384 rows, time-major r = t*64 + b

typedef __attribute__((ext_vector_type(8))) short short8;  // 8 bf16 (4 VGPR) MFMA A/B frag
typedef __attribute__((ext_vector_type(4))) float f32x4;   // MFMA C/D frag

// ---------- bf16 helpers ----------
__device__ __forceinline__ float bf2f(unsigned short u) {
    union { float f; unsigned int i; } v; v.i = ((unsigned int)u) << 16; return v.f;
}
__device__ __forceinline__ unsigned short f2bf(float f) {
    union { float f; unsigned int i; } v; v.f = f;
    unsigned int i = v.i;
    unsigned int r = (i + 0x7FFFu + ((i >> 16) & 1u)) >> 16; // RNE
    return (unsigned short)r;
}
__device__ __forceinline__ float sigm(float x)   { return 1.0f / (1.0f + __expf(-x)); }
__device__ __forceinline__ float tanh_f(float x) { return 2.0f / (1.0f + __expf(-2.0f * x)) - 1.0f; }

// signed byte extract (compiler -> v_bfe_i32)
__device__ __forceinline__ int sb0(int w) { return (w << 24) >> 24; }
__device__ __forceinline__ int sb1(int w) { return (w << 16) >> 24; }
__device__ __forceinline__ int sb2(int w) { return (w <<  8) >> 24; }
__device__ __forceinline__ int sb3(int w) { return  w        >> 24; }

#if defined(__has_builtin)
#if __has_builtin(__builtin_amdgcn_sdot4)
#define HAVE_SDOT4 1
#endif
#endif

// 4x int8 dot product: c += dot(a.bytes, b.bytes)
__device__ __forceinline__ int dot4i8(int a, int b, int c) {
#ifdef HAVE_SDOT4
    return __builtin_amdgcn_sdot4(a, b, c, false);
#else
    return c + sb0(a) * sb0(b) + sb1(a) * sb1(b) + sb2(a) * sb2(b) + sb3(a) * sb3(b);
#endif
}

// accumulate 4 gates for one h-dword against one weight int4
__device__ __forceinline__ void lstm_dot(int hw, int4 wv, int& a0, int& a1, int& a2, int& a3) {
    a0 = dot4i8(hw, wv.x, a0);
    a1 = dot4i8(hw, wv.y, a1);
    a2 = dot4i8(hw, wv.z, a2);
    a3 = dot4i8(hw, wv.w, a3);
}

// barrier that waits only on LDS ops (lgkmcnt), NOT on global loads/stores.
__device__ __forceinline__ void barrier_lgkm() {
    asm volatile("s_waitcnt lgkmcnt(0)\n\ts_barrier" ::: "memory");
}
// single-wave LDS ordering: wave executes in lockstep, so a waitcnt alone
// makes prior ds_writes visible to all lanes -- no s_barrier needed.
__device__ __forceinline__ void wave_lgkm() {
    asm volatile("s_waitcnt lgkmcnt(0)" ::: "memory");
}

// permute gate-major col (g*256+unit) -> interleaved (unit*4+g)
__device__ __forceinline__ int perm_col(int nn) { return ((nn & 255) << 2) | (nn >> 8); }

// ---------- prep: FUSED per-row scale + int8 quantize of Whh (+ acc init) ----------
__global__ __launch_bounds__(64) void conv_quant(
    const float* __restrict__ w0f, const float* __restrict__ w0b,
    const float* __restrict__ w1f, const float* __restrict__ w1b,
    float* __restrict__ S, unsigned int* __restrict__ WQ,
    float* __restrict__ accum)
{
    if (blockIdx.x == 0 && threadIdx.x < 3) accum[threadIdx.x] = 0.0f;  // fused init
    const int m = blockIdx.x >> 10;
    const int r = blockIdx.x & 1023;          // r = g*256 + u
    const float* W = m == 0 ? w0f : m == 1 ? w0b : m == 2 ? w1f : w1b;
    const int t = threadIdx.x;
    const float4 wv = *(const float4*)(W + r * HH + t * 4);  // this thread's 4 k's
    float mx = fmaxf(fmaxf(fabsf(wv.x), fabsf(wv.y)), fmaxf(fabsf(wv.z), fabsf(wv.w)));
    #pragma unroll
    for (int s = 32; s > 0; s >>= 1) mx = fmaxf(mx, __shfl_down(mx, s, 64));
    const float mxall = __shfl(mx, 0, 64);
    const float s = fmaxf(mxall, 1e-20f) / 127.0f;
    const int g = r >> 8, u = r & 255;
    if (t == 0) S[m * 1024 + u * 4 + g] = s;
    int q0 = (int)rintf(wv.x / s), q1 = (int)rintf(wv.y / s);
    int q2 = (int)rintf(wv.z / s), q3 = (int)rintf(wv.w / s);
    q0 = max(-127, min(127, q0)); q1 = max(-127, min(127, q1));
    q2 = max(-127, min(127, q2)); q3 = max(-127, min(127, q3));
    WQ[m * 65536 + (t * 256 + u) * 4 + g] =
        (unsigned int)(q0 & 0xff) | ((unsigned int)(q1 & 0xff) << 8) |
        ((unsigned int)(q2 & 0xff) << 16) | ((unsigned int)(q3 & 0xff) << 24);
}

// ---------- prep: gather embedding rows -> Abf bf16 [16384][320] (zero-pad k>=300) ----------
__global__ __launch_bounds__(320) void conv_gather(
    const int* __restrict__ text, const float* __restrict__ emb,
    unsigned short* __restrict__ Abf)
{
    const int r = blockIdx.x;
    const int k = threadIdx.x;
    const int t = r >> 6, b = r & 63;
    const int idx = text[b * TT + t];
    Abf[r * KP0 + k] = (k < DD) ? f2bf(emb[(size_t)idx * DD + k]) : (unsigned short)0;
}

// ---------- prep: 5 conversions merged: z=0,1 Wih0 (300->320); z=2,3 Wih1 (512); z=4 WsbjT pad ----------
__global__ __launch_bounds__(256) void conv_w5(
    const float* __restrict__ s0, const float* __restrict__ s1,
    const float* __restrict__ s2, const float* __restrict__ s3,
    const float* __restrict__ sW,
    unsigned short* __restrict__ d0, unsigned short* __restrict__ d1,
    unsigned short* __restrict__ d2, unsigned short* __restrict__ d3,
    unsigned short* __restrict__ dW)
{
    const int z = blockIdx.y;
    const int idx = blockIdx.x * 256 + threadIdx.x;
    if (z == 4) {   // Wsbj f32 (37x512) -> bf16 (64x512), rows >= 37 zero
        if (idx >= 64 * 512) return;
        const int r = idx >> 9, cidx = idx & 511;
        dW[idx] = (r < KK) ? f2bf(sW[r * 512 + cidx]) : (unsigned short)0;
        return;
    }
    const float* src = z == 0 ? s0 : z == 1 ? s1 : z == 2 ? s2 : s3;
    unsigned short* dst = z == 0 ? d0 : z == 1 ? d1 : z == 2 ? d2 : d3;
    const int kin   = z < 2 ? DD  : 512;
    const int kout  = z < 2 ? KP0 : 512;
    const int total = 1024 * kout;
    if (idx >= total) return;
    const int rr = idx / kout, k = idx - rr * kout;
    dst[idx] = (k < kin) ? f2bf(src[rr * kin + k]) : (unsigned short)0;
}

// ---------- MFMA GEMM (f+b merged on blockIdx.z): out_z = A @ W_z^T + bias_z ----------
__global__ __launch_bounds__(256) void gemm_mfma2(
    const unsigned short* __restrict__ A,
    const unsigned short* __restrict__ Wf,
    const unsigned short* __restrict__ Wb,
    const float* __restrict__ biasf,
    const float* __restrict__ biasb,
    unsigned short* __restrict__ outf,
    unsigned short* __restrict__ outb,
    int lda)
{
    const unsigned short* W = blockIdx.z ? Wb : Wf;
    const float* bias        = blockIdx.z ? biasb : biasf;
    unsigned short* out      = blockIdx.z ? outb : outf;

    const int bm = blockIdx.x * 128;
    const int bn = blockIdx.y * 128;
    const int tid = threadIdx.x;
    const int lane = tid & 63;
    const int wave = tid >> 6;
    const int wm = (wave & 1) * 64;
    const int wn = (wave >> 1) * 64;

    __shared__ __align__(16) unsigned short As[128 * 32];  // [row][k] 8 KB
    __shared__ __align__(16) unsigned short Bs[128 * 32];  // [wrow][k] 8 KB

    f32x4 acc[4][4] = {};

    const int srow = tid >> 2;          // 0..63
    const int sk = (tid & 3) * 8;       // k element offset (16 B granules)

    const unsigned short* ga0 = A + (size_t)(bm + srow) * lda + sk;
    const unsigned short* ga1 = A + (size_t)(bm + srow + 64) * lda + sk;
    const unsigned short* gb0 = W + (size_t)(bn + srow) * lda + sk;
    const unsigned short* gb1 = W + (size_t)(bn + srow + 64) * lda + sk;

    unsigned short* lA0 = As + wave * 512;
    unsigned short* lA1 = As + 2048 + wave * 512;
    unsigned short* lB0 = Bs + wave * 512;
    unsigned short* lB1 = Bs + 2048 + wave * 512;

    const int kiters = lda >> 5;
    for (int kb = 0; kb < kiters; kb++) {
        const int k0 = kb * 32;
        __builtin_amdgcn_global_load_lds(
            (const __attribute__((address_space(1))) unsigned int*)(ga0 + k0),
            (__attribute__((address_space(3))) unsigned int*)lA0, 16, 0, 0);
        __builtin_amdgcn_global_load_lds(
            (const __attribute__((address_space(1))) unsigned int*)(ga1 + k0),
            (__attribute__((address_space(3))) unsigned int*)lA1, 16, 0, 0);
        __builtin_amdgcn_global_load_lds(
            (const __attribute__((address_space(1))) unsigned int*)(gb0 + k0),
            (__attribute__((address_space(3))) unsigned int*)lB0, 16, 0, 0);
        __builtin_amdgcn_global_load_lds(
            (const __attribute__((address_space(1))) unsigned int*)(gb1 + k0),
            (__attribute__((address_space(3))) unsigned int*)lB1, 16, 0, 0);
        __syncthreads();

        short8 af[4], bfr[4];
        #pragma unroll
        for (int i = 0; i < 4; i++) {
            af[i]  = *(const short8*)&As[(wm + i * 16 + (lane & 15)) * 32 + (lane >> 4) * 8];
            bfr[i] = *(const short8*)&Bs[(wn + i * 16 + (lane & 15)) * 32 + (lane >> 4) * 8];
        }
        #pragma unroll
        for (int i = 0; i < 4; i++)
            #pragma unroll
            for (int j = 0; j < 4; j++)
                acc[i][j] = __builtin_amdgcn_mfma_f32_16x16x32_bf16(af[i], bfr[j], acc[i][j], 0, 0, 0);
        __syncthreads();
    }

    // C/D: col = lane&15, row = (lane>>4)*4 + reg  [measured m89/m91]
    const int cn = lane & 15;
    const int cr = (lane >> 4) * 4;
    #pragma unroll
    for (int j = 0; j < 4; j++) {
        const int n = bn + wn + j * 16 + cn;
        const float bv = bias[n];
        const int pc = perm_col(n);
        #pragma unroll
        for (int i = 0; i < 4; i++) {
            #pragma unroll
            for (int r = 0; r < 4; r++) {
                const int m = bm + wm + i * 16 + cr + r;
                out[(size_t)m * FH + pc] = f2bf(acc[i][j][r] + bv);
            }
        }
    }
}

// ---------- Emission GEMM: em = h1(16384x512 bf16) @ WsbjB(64x512 bf16)^T + bias, f32 out ----------
__global__ __launch_bounds__(256) void gemm_em(
    const unsigned short* __restrict__ A,
    const unsigned short* __restrict__ W,
    const float* __restrict__ bias,
    float* __restrict__ em)
{
    const int bm = blockIdx.x * 128;
    const int tid = threadIdx.x;
    const int lane = tid & 63;
    const int wave = tid >> 6;
    const int wm = (wave & 1) * 64;
    const int wn = (wave >> 1) * 32;

    __shared__ __align__(16) unsigned short As[128 * 32];  // 8 KB
    __shared__ __align__(16) unsigned short Bs[64 * 32];   // 4 KB

    f32x4 acc[4][2] = {};

    const int srow = tid >> 2;          // 0..63
    const int sk = (tid & 3) * 8;

    const unsigned short* ga0 = A + (size_t)(bm + srow) * 512 + sk;
    const unsigned short* ga1 = A + (size_t)(bm + srow + 64) * 512 + sk;
    const unsigned short* gb  = W + (size_t)srow * 512 + sk;

    unsigned short* lA0 = As + wave * 512;
    unsigned short* lA1 = As + 2048 + wave * 512;
    unsigned short* lB  = Bs + wave * 512;

    for (int kb = 0; kb < 16; kb++) {
        const int k0 = kb * 32;
        __builtin_amdgcn_global_load_lds(
            (const __attribute__((address_space(1))) unsigned int*)(ga0 + k0),
            (__attribute__((address_space(3))) unsigned int*)lA0, 16, 0, 0);
        __builtin_amdgcn_global_load_lds(
            (const __attribute__((address_space(1))) unsigned int*)(ga1 + k0),
            (__attribute__((address_space(3))) unsigned int*)lA1, 16, 0, 0);
        __builtin_amdgcn_global_load_lds(
            (const __attribute__((address_space(1))) unsigned int*)(gb + k0),
            (__attribute__((address_space(3))) unsigned int*)lB, 16, 0, 0);
        __syncthreads();

        short8 af[4], bfr[2];
        #pragma unroll
        for (int i = 0; i < 4; i++)
            af[i]  = *(const short8*)&As[(wm + i * 16 + (lane & 15)) * 32 + (lane >> 4) * 8];
        #pragma unroll
        for (int j = 0; j < 2; j++)
            bfr[j] = *(const short8*)&Bs[(wn + j * 16 + (lane & 15)) * 32 + (lane >> 4) * 8];
        #pragma unroll
        for (int i = 0; i < 4; i++)
            #pragma unroll
            for (int j = 0; j < 2; j++)
                acc[i][j] = __builtin_amdgcn_mfma_f32_16x16x32_bf16(af[i], bfr[j], acc[i][j], 0, 0, 0);
        __syncthreads();
    }

    const int cn = lane & 15;
    const int cr = (lane >> 4) * 4;
    #pragma unroll
    for (int j = 0; j < 2; j++) {
        const int n = wn + j * 16 + cn;
        if (n < KK) {
            const float bv = bias[n];
            #pragma unroll
            for (int i = 0; i < 4; i++) {
                #pragma unroll
                for (int r = 0; r < 4; r++) {
                    const int m = bm + wm + i * 16 + cr + r;
                    em[(size_t)m * KK + n] = acc[i][j][r] + bv;
                }
            }
        }
    }
}

// ---------- LSTM recurrence: grid (64 batches, 2 dirs), 512 threads ----------
// R8-PROVEN (245us): split-K depth 2; kh = tid>>8; plain wp[j*256] loads.
// STRUCTURAL FLOOR (R2-R13 evidence): the compiler re-streams the 256 KB
// weight slab from L2 every step no matter what -- plain arrays (R8),
// asm value-pins (R9), AGPR stash (R13) all end in remat/scratch; batch
// merging (R10/R12) halves traffic but starves CUs (449/481us). At 128
// blocks the stream runs at 34 TB/s == the L2 aggregate ceiling ->
// 128 x 256KB x 256 / 34TB/s = 245us. Weights don't fit LDS (256KB > 160KB)
// and cross-block splits need per-step grid sync. DO NOT retry those.
__global__ __launch_bounds__(512, 2) void lstm_kernel(
    const unsigned short* __restrict__ zin_f, const unsigned short* __restrict__ zin_b,
    const int* __restrict__ WQf, const int* __restrict__ WQb,
    const float* __restrict__ Sf, const float* __restrict__ Sb,
    unsigned short* __restrict__ h_out)  // (T,B,512) bf16; fwd cols [0:256), bwd [256:512)
{
    const int dir = blockIdx.y;
    const unsigned short* zin = dir ? zin_b : zin_f;
    const int*   WQ = dir ? WQb : WQf;
    const float* S  = dir ? Sb  : Sf;
    const int off = dir ? HH : 0;

    const int b = blockIdx.x;
    const int tid = threadIdx.x;
    const int u  = tid & 255;
    const int kh = tid >> 8;            // K half, wave-uniform (waves 0-3 / 4-7)

    __shared__ __align__(16) unsigned char hq8[2][HH];  // int8 h, double-buffered
    __shared__ int4 red[HH];                             // kh1 partial sums

    const int4* wp = (const int4*)WQ + kh * 32 * 256 + u;
    int4 w[32];
    #pragma unroll
    for (int j = 0; j < 32; j++) w[j] = wp[j * 256];

    float4 sc = make_float4(0.f, 0.f, 0.f, 0.f);
    if (kh == 0) {
        sc = *(const float4*)(S + 4 * u);
        const float inv127 = 1.0f / 127.0f;
        sc.x *= inv127; sc.y *= inv127; sc.z *= inv127; sc.w *= inv127;
    }
    float c = 0.0f;
    int cur = 0;
    if (tid < 128) ((unsigned int*)hq8)[tid] = 0u;   // zero both buffers
    __syncthreads();

    // prefetch z for step 0 (kh0 lanes only)
    ushort4 zv = make_ushort4(0, 0, 0, 0);
    if (kh == 0) {
        const int tt0 = dir ? (TT - 1) : 0;
        zv = *(const ushort4*)(zin + (tt0 * BB + b) * FH + 4 * u);
    }

    for (int ts = 0; ts < TT; ts++) {
        const int tt = dir ? (TT - 1 - ts) : ts;
        const int row = tt * BB + b;

        // issue NEXT step's zin load now; consumed next iteration
        ushort4 zv_n = make_ushort4(0, 0, 0, 0);
        if (kh == 0) {
            const int ts_n = (ts + 1 < TT) ? (ts + 1) : ts;
            const int tt_n = dir ? (TT - 1 - ts_n) : ts_n;
            zv_n = *(const ushort4*)(zin + (tt_n * BB + b) * FH + 4 * u);
        }

        // h half for this wave-set: 32 dwords via 8x ds_read_b128, uniform addr
        const int4* hv = (const int4*)&hq8[cur][kh * 128];
        int a0 = 0, a1 = 0, a2 = 0, a3 = 0;
        #pragma unroll
        for (int jq = 0; jq < 8; jq++) {
            const int4 hw = hv[jq];
            lstm_dot(hw.x, w[4 * jq + 0], a0, a1, a2, a3);
            lstm_dot(hw.y, w[4 * jq + 1], a0, a1, a2, a3);
            lstm_dot(hw.z, w[4 * jq + 2], a0, a1, a2, a3);
            lstm_dot(hw.w, w[4 * jq + 3], a0, a1, a2, a3);
        }

        if (kh) red[u] = make_int4(a0, a1, a2, a3);
        barrier_lgkm();

        if (kh == 0) {
            const int4 r0 = red[u];
            const int A0 = a0 + r0.x;
            const int A1 = a1 + r0.y;
            const int A2 = a2 + r0.z;
            const int A3 = a3 + r0.w;
            const float zi  = (float)A0 * sc.x + bf2f(zv.x);
            const float zf_ = (float)A1 * sc.y + bf2f(zv.y);
            const float zg  = (float)A2 * sc.z + bf2f(zv.z);
            const float zo  = (float)A3 * sc.w + bf2f(zv.w);
            const float cc = sigm(zf_) * c + sigm(zi) * tanh_f(zg);
            c = cc;
            const float hh = sigm(zo) * tanh_f(cc);
            hq8[cur ^ 1][u] = (unsigned char)((int)rintf(hh * 127.0f));
            h_out[row * (2 * HH) + off + u] = f2bf(hh);
        }
        barrier_lgkm();
        cur ^= 1;
        zv = zv_n;
    }
}

// ---------- CRF: one block (1 wave) per batch; final reduction fused ----------
// Single wave -> LDS cross-lane ordering needs only s_waitcnt lgkmcnt(0),
// no s_barrier (R14). trans column + fused max/sum in registers (R7).
// em row prefetched one step ahead (R8). Last-finishing block computes out.
__global__ __launch_bounds__(64) void crf_kernel(
    const int* __restrict__ text, const int* __restrict__ sbj,
    const float* __restrict__ em,
    const float* __restrict__ start_t, const float* __restrict__ end_t,
    const float* __restrict__ trans, float* __restrict__ accum,
    float* __restrict__ out)
{
    const int b = blockIdx.x;
    const int tid = threadIdx.x;
    __shared__ float tr[KK * KK];
    __shared__ float sc[2][KK];
    for (int x = tid; x < KK * KK; x += 64) tr[x] = trans[x];

    int cnt = 0;
    for (int t = tid; t < TT; t += 64) cnt += (text[b * TT + t] != 0) ? 1 : 0;
    #pragma unroll
    for (int s = 32; s > 0; s >>= 1) cnt += __shfl_down(cnt, s, 64);
    const int len = __shfl(cnt, 0, 64);

    wave_lgkm();   // tr[] visible to all lanes (single wave)

    float part = 0.f;
    for (int t = tid; t < TT; t += 64) {
        if (t >= 1 && t < len) {
            const int tg = sbj[b * TT + t];
            const int tp = sbj[b * TT + t - 1];
            part += em[(t * BB + b) * KK + tg] + tr[tp * KK + tg];
        }
    }
    #pragma unroll
    for (int s = 32; s > 0; s >>= 1) part += __shfl_down(part, s, 64);

    // cache this thread's trans column: tc[k1] = tr[k1][tid]  (t-invariant)
    float tc[KK];
    #pragma unroll
    for (int k1 = 0; k1 < KK; k1++) tc[k1] = (tid < KK) ? tr[k1 * KK + tid] : 0.f;

    if (tid < KK) sc[0][tid] = start_t[tid] + em[b * KK + tid];
    wave_lgkm();
    int cur = 0;
    // prefetch em row for t=1
    float ev = (tid < KK && len > 1) ? em[(BB + b) * KK + tid] : 0.f;
    for (int t = 1; t < len; t++) {
        // prefetch next step's em row (consumed next iteration)
        const float ev_n = (tid < KK && t + 1 < len) ? em[((t + 1) * BB + b) * KK + tid] : 0.f;
        float nv = 0.f;
        if (tid < KK) {
            float v[KK];
            float mx = -1e30f;
            #pragma unroll
            for (int k1 = 0; k1 < KK; k1++) {
                v[k1] = sc[cur][k1] + tc[k1];
                mx = fmaxf(mx, v[k1]);
            }
            float s = 0.f;
            #pragma unroll
            for (int k1 = 0; k1 < KK; k1++)
                s += __expf(v[k1] - mx);
            nv = mx + __logf(s) + ev;
        }
        if (tid < KK) sc[cur ^ 1][tid] = nv;
        wave_lgkm();
        cur ^= 1;
        ev = ev_n;
    }

    if (tid == 0) {
        const int tg0 = sbj[b * TT];
        const int tgl = sbj[b * TT + len - 1];
        const float num = start_t[tg0] + em[b * KK + tg0] + part + end_t[tgl];
        float mx = -1e30f;
        for (int k = 0; k < KK; k++) mx = fmaxf(mx, sc[cur][k] + end_t[k]);
        float s = 0.f;
        for (int k = 0; k < KK; k++) s += __expf(sc[cur][k] + end_t[k] - mx);
        const float logZ = mx + __logf(s);
        atomicAdd(&accum[0], num - logZ);
        atomicAdd(&accum[1], (float)len);
        __threadfence();
        const float done = atomicAdd(&accum[2], 1.0f);
        if (done == (float)(BB - 1)) {      // last block: fused final_kernel
            const float llh = atomicAdd(&accum[0], 0.0f);   // atomic read
            const float tot = atomicAdd(&accum[1], 0.0f);
            out[0] = -(llh / tot);
        }
    }
}

// ---------- launch ----------
extern "C" void kernel_launch(void* const* d_in, const int* in_sizes, int n_in,
                              void* d_out, int out_size, void* d_ws, size_t ws_size,
                              hipStream_t stream)
{
    (void)in_sizes; (void)n_in; (void)out_size; (void)ws_size;
    const int*   text  = (const int*)d_in[0];
    const int*   sbj   = (const int*)d_in[1];
    const float* emb   = (const float*)d_in[2];
    const float* Wih0f = (const float*)d_in[3];
    const float* Whh0f = (const float*)d_in[4];
    const float* b0f   = (const float*)d_in[5];
    const float* Wih0b = (const float*)d_in[6];
    const float* Whh0b = (const float*)d_in[7];
    const float* b0b   = (const float*)d_in[8];
    const float* Wih1f = (const float*)d_in[9];
    const float* Whh1f = (const float*)d_in[10];
    const float* b1f   = (const float*)d_in[11];
    const float* Wih1b = (const float*)d_in[12];
    const float* Whh1b = (const float*)d_in[13];
    const float* b1b   = (const float*)d_in[14];
    const float* Wsbj  = (const float*)d_in[15];
    const float* bsbj  = (const float*)d_in[16];
    const float* start_t = (const float*)d_in[17];
    const float* end_t   = (const float*)d_in[18];
    const float* trans   = (const float*)d_in[19];

    // workspace map (bytes), max ~102.84 MB. Overlaps (stream-ordered lifetimes):
    char* ws = (char*)d_ws;
    unsigned short* zf   = (unsigned short*)(ws + 0);           // 32 MiB
    unsigned short* zb   = (unsigned short*)(ws + 33554432);    // 32 MiB
    unsigned short* h0   = (unsigned short*)(ws + 67108864);    // 16 MiB
    unsigned short* h1   = (unsigned short*)(ws + 83886080);    // 16 MiB
    unsigned short* Wb0f = (unsigned short*)(ws + 67108864);    // 1024x320 bf16
    unsigned short* Wb0b = (unsigned short*)(ws + 67764224);
    unsigned short* Abf  = (unsigned short*)(ws + 83886080);    // 16384x320 bf16 (10 MiB)
    unsigned short* Wb1f = (unsigned short*)(ws + 94371840);    // 1024x512 bf16
    unsigned short* Wb1b = (unsigned short*)(ws + 95420416);
    unsigned int*   WQ   = (unsigned int*)(ws + 100663296);     // 4 x 256 KiB int8 weights
    float*          Sq   = (float*)(ws + 101711872);            // 4 x 4 KiB scales
    unsigned short* WsbjB = (unsigned short*)(ws + 102760448);  // 64x512 bf16 (64 KiB)
    float*          acc  = (float*)(ws + 102836224);            // 12 B (llh, len, done)
    float*           em  = (float*)(ws + 0);                    // 2.4 MiB (over zf)
    float* out = (float*)d_out;

    const int* WQ0f = (const int*)(WQ + 0 * 65536);
    const int* WQ0b = (const int*)(WQ + 1 * 65536);
    const int* WQ1f = (const int*)(WQ + 2 * 65536);
    const int* WQ1b = (const int*)(WQ + 3 * 65536);
    const float* S0f = Sq + 0 * 1024;
    const float* S0b = Sq + 1 * 1024;
    const float* S1f = Sq + 2 * 1024;
    const float* S1b = Sq + 3 * 1024;

    conv_quant<<<dim3(4096), 64, 0, stream>>>(Whh0f, Whh0b, Whh1f, Whh1b, Sq, WQ, acc);
    conv_gather<<<dim3(MTOT), 320, 0, stream>>>(text, emb, Abf);
    conv_w5<<<dim3(2048, 5), 256, 0, stream>>>(Wih0f, Wih0b, Wih1f, Wih1b, Wsbj,
                                               Wb0f, Wb0b, Wb1f, Wb1b, WsbjB);

    // layer 0 input projection (MFMA), f+b in one dispatch
    gemm_mfma2<<<dim3(128, 8, 2), 256, 0, stream>>>(Abf, Wb0f, Wb0b, b0f, b0b, zf, zb, KP0);
    lstm_kernel<<<dim3(BB, 2), 512, 0, stream>>>(zf, zb, WQ0f, WQ0b, S0f, S0b, h0);
    // layer 1 input projection (MFMA), f+b in one dispatch
    gemm_mfma2<<<dim3(128, 8, 2), 256, 0, stream>>>(h0, Wb1f, Wb1b, b1f, b1b, zf, zb, 512);
    lstm_kernel<<<dim3(BB, 2), 512, 0, stream>>>(zf, zb, WQ1f, WQ1b, S1f, S1b, h1);

    gemm_em<<<dim3(128), 256, 0, stream>>>(h1, WsbjB, bsbj, em);
    crf_kernel<<<BB, 64, 0, stream>>>(text, sbj, em, start_t, end_t, trans, acc, out);
}